// Round 7
// baseline (372.993 us; speedup 1.0000x reference)
//
#include <hip/hip_runtime.h>

#define HIDDEN 2048
#define NHEADS 32
#define NKV 8
#define HD 64
#define BATCH 2
#define SEQ 2048
#define MROWS (BATCH*SEQ)        // 4096
#define KVDIM (NKV*HD)           // 512
#define QKVN (HIDDEN + 2*KVDIM)  // 3072

typedef __bf16 bf16x8 __attribute__((ext_vector_type(8)));
typedef float f32x4 __attribute__((ext_vector_type(4)));

// async global->LDS, 16B per lane; lds base must be wave-uniform (HW: base + lane*16)
__device__ inline void gld16(const __bf16* g, __bf16* l) {
    __builtin_amdgcn_global_load_lds((const __attribute__((address_space(1))) void*)g,
                                     (__attribute__((address_space(3))) void*)l, 16, 0, 0);
}

// ---------------- fused cast fp32 -> bf16 for all 5 tensors ----------------
__global__ __launch_bounds__(256) void cast_all(const float* __restrict__ x,
                                                const float* __restrict__ wq,
                                                const float* __restrict__ wk,
                                                const float* __restrict__ wv,
                                                const float* __restrict__ wo,
                                                __bf16* __restrict__ xb,
                                                __bf16* __restrict__ wqkv,
                                                __bf16* __restrict__ wob,
                                                float qscale) {
    int blk = blockIdx.x;
    const float* src; __bf16* dst; float sc = 1.0f; size_t off;
    if (blk < 8192)        { src = x;  dst = xb;   off = (size_t)blk * 1024; }
    else if (blk < 12288)  { src = wq; dst = wqkv; off = (size_t)(blk - 8192) * 1024; sc = qscale; }
    else if (blk < 13312)  { src = wk; dst = wqkv + (size_t)HIDDEN * HIDDEN; off = (size_t)(blk - 12288) * 1024; }
    else if (blk < 14336)  { src = wv; dst = wqkv + (size_t)(HIDDEN + KVDIM) * HIDDEN; off = (size_t)(blk - 13312) * 1024; }
    else                   { src = wo; dst = wob;  off = (size_t)(blk - 14336) * 1024; }
    size_t i4 = off + (size_t)threadIdx.x * 4;
    float4 f = *(const float4*)(src + i4);
    dst[i4 + 0] = (__bf16)(f.x * sc);
    dst[i4 + 1] = (__bf16)(f.y * sc);
    dst[i4 + 2] = (__bf16)(f.z * sc);
    dst[i4 + 3] = (__bf16)(f.w * sc);
}

__device__ inline void store_val(__bf16* C, size_t idx, float v) { C[idx] = (__bf16)v; }
__device__ inline void store_val(float* C, size_t idx, float v) { C[idx] = v; }

// ---------------- GEMM: C = A(M,K) @ B(N,K)^T; double-buffered LDS, BK=32 -----
template <typename OutT>
__global__ __launch_bounds__(256) void gemm128(const __bf16* __restrict__ A,
                                               const __bf16* __restrict__ B,
                                               OutT* __restrict__ C,
                                               int M, int N, int K) {
    __shared__ __bf16 As[2][128][32];
    __shared__ __bf16 Bs[2][128][32];
    const int tid  = threadIdx.x;
    const int lane = tid & 63;
    const int w    = tid >> 6;
    const int col  = lane & 15;
    const int quad = lane >> 4;
    const int m0 = blockIdx.y * 128;
    const int n0 = blockIdx.x * 128;
    const int wm = (w >> 1) * 64;
    const int wn = (w & 1) * 64;

    f32x4 acc[4][4];
    #pragma unroll
    for (int i = 0; i < 4; i++)
        #pragma unroll
        for (int j = 0; j < 4; j++) acc[i][j] = (f32x4){0.f,0.f,0.f,0.f};

    const int lrow = lane >> 2;        // 0..15
    const int lcol = (lane & 3) * 8;   // 0,8,16,24

    auto stage = [&](int k0, int buf) {
        #pragma unroll
        for (int c = 0; c < 4; c++) {
            int chunk = w * 4 + c;
            if (chunk < 8) {
                const __bf16* g = A + (size_t)(m0 + chunk*16 + lrow) * K + k0 + lcol;
                gld16(g, &As[buf][chunk*16][0]);
            } else {
                int bc = chunk - 8;
                const __bf16* g = B + (size_t)(n0 + bc*16 + lrow) * K + k0 + lcol;
                gld16(g, &Bs[buf][bc*16][0]);
            }
        }
    };

    const int nk = K / 32;
    stage(0, 0);
    for (int ki = 0; ki < nk; ki++) {
        const int buf = ki & 1;
        __syncthreads();                      // drains stage(ki) DMA; frees buf^1
        if (ki + 1 < nk) stage((ki + 1) * 32, buf ^ 1);   // overlaps compute below

        bf16x8 af[4], bfr[4];
        #pragma unroll
        for (int i = 0; i < 4; i++) af[i]  = *(const bf16x8*)&As[buf][wm + i*16 + col][quad*8];
        #pragma unroll
        for (int j = 0; j < 4; j++) bfr[j] = *(const bf16x8*)&Bs[buf][wn + j*16 + col][quad*8];
        #pragma unroll
        for (int i = 0; i < 4; i++)
            #pragma unroll
            for (int j = 0; j < 4; j++)
                acc[i][j] = __builtin_amdgcn_mfma_f32_16x16x32_bf16(af[i], bfr[j], acc[i][j], 0, 0, 0);
    }

    #pragma unroll
    for (int i = 0; i < 4; i++) {
        #pragma unroll
        for (int r = 0; r < 4; r++) {
            int mrow = m0 + wm + i*16 + quad*4 + r;
            size_t base = (size_t)mrow * N + n0 + wn;
            #pragma unroll
            for (int j = 0; j < 4; j++)
                store_val(C, base + j*16 + col, acc[i][j][r]);
        }
    }
}

// ---------------- V transpose: VT[kvh*64+d][b*S+s] = QKV[b*S+s][2560 + kvh*64+d] ----
__global__ __launch_bounds__(256) void transpose_v(const __bf16* __restrict__ QKV,
                                                   __bf16* __restrict__ VT) {
    __shared__ __bf16 tile[64][72];
    const int r0 = blockIdx.x * 64;
    const int s0 = blockIdx.y * 64;
    const int t  = threadIdx.x;
    #pragma unroll
    for (int cc = 0; cc < 2; cc++) {
        int c = t + cc * 256;
        int i = c >> 3;
        int j8 = (c & 7) * 8;
        bf16x8 v = *(const bf16x8*)(QKV + (size_t)(s0 + i) * QKVN + (HIDDEN + KVDIM) + r0 + j8);
        *(bf16x8*)&tile[i][j8] = v;
    }
    __syncthreads();
    #pragma unroll
    for (int cc = 0; cc < 2; cc++) {
        int c = t + cc * 256;
        int d = c >> 3;
        int sc = (c & 7) * 8;
        bf16x8 vv;
        #pragma unroll
        for (int j = 0; j < 8; j++) vv[j] = tile[sc + j][d];
        *(bf16x8*)(VT + (size_t)(r0 + d) * MROWS + s0 + sc) = vv;
    }
}

// ---------------- flash attention: complementary pairs + split-k x2 ------------
// Fixed-max softmax => partials are ADDITIVE: each half e in {0,1} handles
// k-tiles kt ≡ e (mod 2), writes unnormalized o (bf16) + row-sum l (f32);
// combine kernel sums halves and divides. Block = 4 waves, q-tiles p & 31-p,
// 64-kpos K/V tiles, 2 barriers/tile (R5 structure). H and L subtiles processed
// sequentially reusing a 16-row Pt -> LDS 25.6 KB -> 6 blocks/CU; lb(256,6)
// caps VGPR at 85 -> 24 waves/CU resident.
__global__ __launch_bounds__(256, 6) void flash_attn(const __bf16* __restrict__ QKV,
                                                     const __bf16* __restrict__ VT,
                                                     __bf16* __restrict__ OP,
                                                     float* __restrict__ LP) {
    const int e    = blockIdx.x & 1;
    const int p    = (blockIdx.x >> 1) & 15;
    const int head = (blockIdx.x >> 5) & 31;
    const int b    = blockIdx.x >> 10;
    const int kvh  = head >> 2;
    const int tid  = threadIdx.x;
    const int lane = tid & 63;
    const int w    = tid >> 6;
    const int col  = lane & 15;
    const int quad = lane >> 4;

    const int qbL = p * 64 + w * 16;          // light tile rows
    const int qbH = (31 - p) * 64 + w * 16;   // heavy tile rows
    const int np  = p + 1;                    // light k-tiles (64-granular)
    const int nh  = 32 - p;                   // heavy k-tiles

    __shared__ __bf16 Ks[2][64][32];   // [d-half][kpos][d32]   8 KB
    __shared__ __bf16 Vs[2][64][32];   // [k-half][d][kpos32]   8 KB
    __shared__ __bf16 Pt[4][16][72];   // per-wave P, one subtile at a time 9 KB

    const size_t bS = (size_t)b * SEQ;
    const size_t qLg = (bS + qbL + col) * QKVN + head * HD;
    const size_t qHg = (bS + qbH + col) * QKVN + head * HD;
    bf16x8 aqL0 = *(const bf16x8*)(QKV + qLg + quad * 8);
    bf16x8 aqL1 = *(const bf16x8*)(QKV + qLg + 32 + quad * 8);
    bf16x8 aqH0 = *(const bf16x8*)(QKV + qHg + quad * 8);
    bf16x8 aqH1 = *(const bf16x8*)(QKV + qHg + 32 + quad * 8);

    bf16x8 ones;
    #pragma unroll
    for (int j = 0; j < 8; j++) ones[j] = (__bf16)1.0f;

    f32x4 oL[4], oH[4];
    #pragma unroll
    for (int dn = 0; dn < 4; dn++) { oL[dn] = (f32x4){0.f,0.f,0.f,0.f}; oH[dn] = (f32x4){0.f,0.f,0.f,0.f}; }
    f32x4 lsumL = (f32x4){0.f,0.f,0.f,0.f};
    f32x4 lsumH = (f32x4){0.f,0.f,0.f,0.f};

    const int lrow = lane >> 2;          // 0..15
    const int lcol = (lane & 3) * 8;     // 0,8,16,24

    auto stage = [&](int kbase) {
        #pragma unroll
        for (int c = 0; c < 4; c++) {
            int chunk = w * 4 + c;
            if (chunk < 8) {
                int h = chunk >> 2, rb = chunk & 3;
                const __bf16* g = QKV + (bS + kbase + rb*16 + lrow) * QKVN
                                      + HIDDEN + kvh * HD + h * 32 + lcol;
                gld16(g, &Ks[h][rb*16][0]);
            } else {
                int vc = chunk - 8; int h = vc >> 2, db = vc & 3;
                const __bf16* g = VT + (size_t)(kvh * HD + db*16 + lrow) * MROWS
                                     + bS + kbase + h * 32 + lcol;
                gld16(g, &Vs[h][db*16][0]);
            }
        }
    };

    // one 16x64 subtile: QK^T -> exp2 -> Pt roundtrip -> lsum & PV accumulate
    auto phase = [&](bf16x8 aq0, bf16x8 aq1, int qb, bool do_mask, int kbase,
                     f32x4* o, f32x4& lsum) {
        #pragma unroll
        for (int jj = 0; jj < 2; jj++) {
            f32x4 s[2];
            s[0] = (f32x4){0.f,0.f,0.f,0.f};
            s[1] = (f32x4){0.f,0.f,0.f,0.f};
            #pragma unroll
            for (int jz = 0; jz < 2; jz++) {
                int j = jj*2 + jz;
                bf16x8 bk0 = *(const bf16x8*)&Ks[0][j*16 + col][quad*8];
                bf16x8 bk1 = *(const bf16x8*)&Ks[1][j*16 + col][quad*8];
                s[jz] = __builtin_amdgcn_mfma_f32_16x16x32_bf16(aq0, bk0, s[jz], 0, 0, 0);
                s[jz] = __builtin_amdgcn_mfma_f32_16x16x32_bf16(aq1, bk1, s[jz], 0, 0, 0);
            }
            if (do_mask) {
                #pragma unroll
                for (int r = 0; r < 4; r++) {
                    int qrow = qb + quad*4 + r;
                    #pragma unroll
                    for (int jz = 0; jz < 2; jz++)
                        if (kbase + (jj*2+jz)*16 + col > qrow) s[jz][r] = -1e30f;
                }
            }
            #pragma unroll
            for (int r = 0; r < 4; r++) {
                int pr = quad*4 + r;
                Pt[w][pr][(jj*2)*16 + col]   = (__bf16)__builtin_amdgcn_exp2f(s[0][r]);
                Pt[w][pr][(jj*2+1)*16 + col] = (__bf16)__builtin_amdgcn_exp2f(s[1][r]);
            }
        }
        __asm__ volatile("s_waitcnt lgkmcnt(0)" ::: "memory");
        bf16x8 ap0 = *(const bf16x8*)&Pt[w][col][quad*8];
        bf16x8 ap1 = *(const bf16x8*)&Pt[w][col][32 + quad*8];
        lsum = __builtin_amdgcn_mfma_f32_16x16x32_bf16(ap0, ones, lsum, 0, 0, 0);
        lsum = __builtin_amdgcn_mfma_f32_16x16x32_bf16(ap1, ones, lsum, 0, 0, 0);
        #pragma unroll
        for (int dn = 0; dn < 4; dn++) {
            bf16x8 bv0 = *(const bf16x8*)&Vs[0][dn*16 + col][quad*8];
            bf16x8 bv1 = *(const bf16x8*)&Vs[1][dn*16 + col][quad*8];
            o[dn] = __builtin_amdgcn_mfma_f32_16x16x32_bf16(ap0, bv0, o[dn], 0, 0, 0);
            o[dn] = __builtin_amdgcn_mfma_f32_16x16x32_bf16(ap1, bv1, o[dn], 0, 0, 0);
        }
    };

    for (int kt = e; kt < nh; kt += 2) {
        const int kbase = kt * 64;
        __syncthreads();                 // protect previous iteration's LDS reads
        stage(kbase);
        __syncthreads();                 // DMA drained -> LDS valid
        phase(aqH0, aqH1, qbH, kt == nh - 1, kbase, oH, lsumH);
        if (kt < np)
            phase(aqL0, aqL1, qbL, kt == np - 1, kbase, oL, lsumL);
    }

    // write partials (always: buffers are poisoned each launch)
    const size_t eoff = (size_t)e * MROWS * HIDDEN;
    #pragma unroll
    for (int r = 0; r < 4; r++) {
        __bf16* opH = OP + eoff + (bS + qbH + quad*4 + r) * HIDDEN + head * HD;
        __bf16* opL = OP + eoff + (bS + qbL + quad*4 + r) * HIDDEN + head * HD;
        #pragma unroll
        for (int dn = 0; dn < 4; dn++) {
            opH[dn*16 + col] = (__bf16)oH[dn][r];
            opL[dn*16 + col] = (__bf16)oL[dn][r];
        }
    }
    if (col == 0) {
        float* lp = LP + (size_t)(e * NHEADS + head) * MROWS + bS;
        #pragma unroll
        for (int r = 0; r < 4; r++) {
            lp[qbH + quad*4 + r] = lsumH[r];
            lp[qbL + quad*4 + r] = lsumL[r];
        }
    }
}

// ---------------- combine: out = (oA + oB) / (lA + lB) ----------------
__global__ __launch_bounds__(256) void combine(const __bf16* __restrict__ OP,
                                               const float* __restrict__ LP,
                                               __bf16* __restrict__ out) {
    size_t idx = ((size_t)blockIdx.x * 256 + threadIdx.x) * 8;
    int g = (int)(idx >> 11);          // global row (HIDDEN = 2048)
    int c = (int)(idx & (HIDDEN - 1));
    int head = c >> 6;
    float l = LP[(size_t)head * MROWS + g] + LP[(size_t)(NHEADS + head) * MROWS + g];
    float inv = 1.0f / l;
    bf16x8 a = *(const bf16x8*)(OP + idx);
    bf16x8 bb = *(const bf16x8*)(OP + (size_t)MROWS * HIDDEN + idx);
    bf16x8 o;
    #pragma unroll
    for (int j = 0; j < 8; j++)
        o[j] = (__bf16)(((float)a[j] + (float)bb[j]) * inv);
    *(bf16x8*)(out + idx) = o;
}

// ---------------- launch ----------------
extern "C" void kernel_launch(void* const* d_in, const int* in_sizes, int n_in,
                              void* d_out, int out_size, void* d_ws, size_t ws_size,
                              hipStream_t stream) {
    const float* x  = (const float*)d_in[0];
    const float* Wq = (const float*)d_in[1];
    const float* Wk = (const float*)d_in[2];
    const float* Wv = (const float*)d_in[3];
    const float* Wo = (const float*)d_in[4];
    float* out = (float*)d_out;

    __bf16* p    = (__bf16*)d_ws;
    __bf16* xb   = p; p += (size_t)MROWS * HIDDEN;
    __bf16* wqkv = p; p += (size_t)QKVN * HIDDEN;
    __bf16* wob  = p; p += (size_t)HIDDEN * HIDDEN;
    __bf16* qkv  = p; p += (size_t)MROWS * QKVN;
    __bf16* vt   = p; p += (size_t)KVDIM * MROWS;
    __bf16* op   = p; p += (size_t)2 * MROWS * HIDDEN;   // split-k partials
    float*  lp   = (float*)p; p += (size_t)2 * NHEADS * MROWS * 2;  // f32 = 2 bf16 slots
    __bf16* aob  = xb;   // alias: x not needed post-projection

    const float qscale = 0.125f * 1.4426950408889634f;
    cast_all<<<18432, 256, 0, stream>>>(x, Wq, Wk, Wv, Wo, xb, wqkv, wob, qscale);

    dim3 blk(256);
    gemm128<__bf16><<<dim3(QKVN/128, MROWS/128), blk, 0, stream>>>(xb, wqkv, qkv, MROWS, QKVN, HIDDEN);
    transpose_v<<<dim3(KVDIM/64, MROWS/64), blk, 0, stream>>>(qkv, vt);
    flash_attn<<<2 * BATCH * NHEADS * (SEQ/128), blk, 0, stream>>>(qkv, vt, op, lp);
    combine<<<(MROWS * HIDDEN) / (256 * 8), blk, 0, stream>>>(op, lp, aob);
    gemm128<float><<<dim3(HIDDEN/128, MROWS/128), blk, 0, stream>>>(aob, wob, out, MROWS, HIDDEN, HIDDEN);
}